// Round 10
// baseline (2343.514 us; speedup 1.0000x reference)
//
#include <hip/hip_runtime.h>

#define T_STEPS 1000
#define BATCH   256
#define IN_DIM  128
#define HID     512
#define OUT_DIM 32
#define ALPHA_F 0.2f
#define OMA_F   0.8f
#define MAXNNZ  96   // Binomial(511,0.1) max over 512 rows ~ 75; 96 is 6.5 sigma
#define BDEPTH  20   // per-(lane,bank) bucket depth; P(overflow) ~ 0

// ---- workspace layout (byte offsets, all 16B aligned) ----
// val_t : float  [HID][MAXNNZ]   rank-ordered rows      @ 0        (196608 B)
// idx_t : ushort [HID][MAXNNZ]   byte offsets (j*4)     @ 196608   (98304 B)
// perm  : uint   [HID]           rank -> row            @ 294912   (2048 B)
// nnzR  : uint   [HID]           nnz (later: sched S)   @ 296960   (2048 B)
// w_inT : float  [IN_DIM][HID]                          @ 299008   (262144 B)
// fcT   : float  [HID][OUT_DIM]                         @ 561152   (65536 B)

// ============================================================
// K2a: counts + deterministic rank (stable sort by (c, h)).
// ============================================================
__global__ __launch_bounds__(512) void build_rank_kernel(
    const float* __restrict__ w_h, const float* __restrict__ sparse,
    unsigned int* __restrict__ perm, unsigned int* __restrict__ nnzR)
{
    int tid = threadIdx.x;           // row h
    __shared__ int cnt_sh[HID];

    const float4* wr4 = (const float4*)(w_h    + tid * HID);
    const float4* sr4 = (const float4*)(sparse + tid * HID);
    int cnt = 0;
    for (int j4 = 0; j4 < HID / 4; j4++) {
        float4 w = wr4[j4];
        float4 s = sr4[j4];
        if (w.x > 0.f && s.x > 0.5f) cnt++;
        if (w.y > 0.f && s.y > 0.5f) cnt++;
        if (w.z > 0.f && s.z > 0.5f) cnt++;
        if (w.w > 0.f && s.w > 0.5f) cnt++;
    }
    int c = min(cnt, MAXNNZ);

    cnt_sh[tid] = c;
    __syncthreads();
    int rank = 0;
    for (int j = 0; j < HID; j++) {
        int cj = cnt_sh[j];                     // broadcast read
        rank += (cj < c) || (cj == c && j < tid);
    }
    perm[rank] = (unsigned int)tid;
    nnzR[rank] = (unsigned int)c;
}

// ============================================================
// K2b: wave-parallel fill, one rank per block (1 wave).
//      Ascending-j compaction via ballot prefix (deterministic).
// ============================================================
__global__ __launch_bounds__(64) void fill_kernel(
    const float* __restrict__ w_h, const float* __restrict__ dale,
    const float* __restrict__ sparse,
    const unsigned int* __restrict__ perm, const unsigned int* __restrict__ nnzR,
    float* __restrict__ val_t, unsigned short* __restrict__ idx_t)
{
    int r    = blockIdx.x;           // rank
    int lane = threadIdx.x;          // 0..63
    int h = (int)perm[r];
    int c = (int)nnzR[r];

    float*          vout = val_t + r * MAXNNZ;
    unsigned short* iout = idx_t + r * MAXNNZ;

    for (int k = lane; k < MAXNNZ; k += 64)
        if (k >= c) { vout[k] = 0.f; iout[k] = 0; }

    unsigned long long lt = (1ull << lane) - 1ull;
    int pos_base = 0;
#pragma unroll
    for (int ch = 0; ch < 8; ch++) {
        int j = ch * 64 + lane;
        float w = w_h[h * HID + j];
        float s = sparse[h * HID + j];
        bool pred = (w > 0.f) && (s > 0.5f);
        unsigned long long m = __ballot(pred);
        if (pred) {
            int pos = pos_base + (int)__popcll(m & lt);
            if (pos < MAXNNZ) {
                vout[pos] = w * dale[j];
                iout[pos] = (unsigned short)(j * 4);   // LDS byte offset
            }
        }
        pos_base += (int)__popcll(m);
    }
}

// ============================================================
// K2d: ballot-parallel conflict-free gather scheduler. 1 wave per
//  scan wave. S = max(wave-max nnz, per-group max bank load) ->
//  a conflict-free schedule exists (Konig); greedy: per slot, each
//  lane proposes a bank (rotated-ffs), per-bank full-wave ballot
//  resolves winner = HIGHEST lane (nnz-sorted -> tight lanes win),
//  3 rounds + forced fallback (invariant rem <= S-s: no drops).
//  Integer-only, lane-ordered, LDS atomics are int sums ->
//  fully deterministic. ~40-60us on 8 CUs (R8's was ~500us).
// ============================================================
__global__ __launch_bounds__(64) void sched_kernel(
    float* __restrict__ val_t, unsigned short* __restrict__ idx_t,
    unsigned int* __restrict__ nnzR)
{
    int w    = blockIdx.x;           // scan-wave id 0..7
    int lane = threadIdx.x;          // 0..63
    int rank = w * 64 + lane;
    int g    = lane >> 5;            // phase-group 0/1
    int l32  = lane & 31;
    unsigned long long gmask = 0xFFFFFFFFull << (g * 32);

    __shared__ unsigned short entb[64][32][BDEPTH]; // (src<<9)|word
    __shared__ unsigned char  cntb[64][32];
    __shared__ unsigned char  outsrc[64][MAXNNZ];
    __shared__ float          vll[64][MAXNNZ];
    __shared__ int            loads[2][32];

    int c = (int)nnzR[rank];
    int cmax = c;
#pragma unroll
    for (int off = 32; off; off >>= 1) cmax = max(cmax, __shfl_xor(cmax, off));

    if (lane < 32) { loads[0][lane] = 0; loads[1][lane] = 0; }
    for (int b = 0; b < 32; b++) cntb[lane][b] = 0;
    for (int e = 0; e < MAXNNZ; e++) {
        vll[lane][e]    = val_t[rank * MAXNNZ + e];
        outsrc[lane][e] = 255;
    }
    unsigned int bm = 0;
    int rem = 0;
    for (int e = 0; e < c; e++) {
        int word = ((int)idx_t[rank * MAXNNZ + e]) >> 2;  // 0..511
        int b = word & 31;
        int k = (int)cntb[lane][b];
        if (k < BDEPTH) {
            entb[lane][b][k] = (unsigned short)((e << 9) | word);
            cntb[lane][b] = (unsigned char)(k + 1);
            bm |= 1u << b;
            rem++;
        }
    }
    __syncthreads();
    for (int b = 0; b < 32; b++)
        if (cntb[lane][b]) atomicAdd(&loads[g][b], (int)cntb[lane][b]);
    __syncthreads();
    int ml = 0;
    if (lane < 32) ml = max(loads[0][lane], loads[1][lane]);
#pragma unroll
    for (int off = 32; off; off >>= 1) ml = max(ml, __shfl_xor(ml, off));
    int S = min(max(cmax, ml), MAXNNZ);              // wave-uniform

    for (int s = 0; s < MAXNNZ; s++) {
        if (s < S) {
            unsigned int claimed = 0;                // my group's claimed banks
            int myb = -1;
            for (int round = 0; round < 3; round++) {
                int prop = -1;
                if (rem > 0 && myb < 0) {
                    unsigned int avail = bm & ~claimed;
                    if (avail) {
                        int rot = (l32 * 5 + s * 3 + round * 11) & 31;
                        unsigned int av2 = (avail >> rot) | (avail << ((32 - rot) & 31));
                        int p = __ffs(av2) - 1;
                        prop = (p + rot) & 31;
                    }
                }
                if (__ballot(prop >= 0) == 0ull) continue;   // wave-uniform
                for (int b = 0; b < 32; b++) {
                    unsigned long long m  = __ballot(prop == b);
                    unsigned long long mg = m & gmask;
                    if (mg) {
                        claimed |= 1u << b;
                        int winner = 63 - __clzll(mg);       // highest lane wins
                        if (lane == winner) myb = b;
                    }
                }
            }
            if (myb < 0 && rem > 0 && rem >= S - s) {        // forced (rare)
                unsigned int a = bm & ~claimed;
                myb = a ? (__ffs(a) - 1) : (__ffs(bm) - 1);
            }
            if (myb >= 0) {
                int k = (int)cntb[lane][myb] - 1;
                unsigned short pk = entb[lane][myb][k];
                cntb[lane][myb] = (unsigned char)k;
                if (k == 0) bm &= ~(1u << myb);
                outsrc[lane][s] = (unsigned char)(pk >> 9);
                idx_t[rank * MAXNNZ + s] = (unsigned short)((pk & 511) * 4);
                rem--;
            } else {
                unsigned int freeb = ~claimed;               // pad: free bank
                int pb = freeb ? (__ffs(freeb) - 1) : 0;
                idx_t[rank * MAXNNZ + s] = (unsigned short)(pb * 4);
            }
        } else {
            idx_t[rank * MAXNNZ + s] = 0;    // tail pad (read by chunk rounding)
        }
    }
    nnzR[rank] = (unsigned int)S;

    for (int s = 0; s < MAXNNZ; s++) {
        int src = outsrc[lane][s];
        val_t[rank * MAXNNZ + s] = (src == 255) ? 0.f : vll[lane][src];
    }
}

// ============================================================
// K2c: weight transposes, grid-parallel.
// ============================================================
__global__ __launch_bounds__(256) void trans_kernel(
    const float* __restrict__ w_in, const float* __restrict__ fc_w,
    float* __restrict__ w_inT, float* __restrict__ fcT)
{
    int o = blockIdx.x * 256 + threadIdx.x;
    if (o < IN_DIM * HID) {
        int k = o / HID, n = o % HID;          // w_inT[k][n] = w_in[n][k]
        w_inT[o] = w_in[n * IN_DIM + k];
    } else {
        int o2 = o - IN_DIM * HID;
        if (o2 < HID * OUT_DIM) {
            int k = o2 / OUT_DIM, oo = o2 % OUT_DIM;   // fcT[k][o] = fc_w[o][k]
            fcT[o2] = fc_w[oo * HID + k];
        }
    }
}

// ============================================================
// K1: xd[m][h] = x[m]@w_in^T + b_in + b_h  into activity slab.
//     Grid 16000 = 1000 m-tiles x 16 n-chunks (XCD-swizzled).
//     k-tile 32 in LDS (33 KB -> 4 blocks/CU, 16 waves/CU).
// ============================================================
__global__ __launch_bounds__(256, 4) void ingemm_kernel(
    const float* __restrict__ x, const float* __restrict__ w_inT,
    const float* __restrict__ b_in, const float* __restrict__ b_h,
    float* __restrict__ xd)
{
    __shared__ float xl[256 * 33];   // [row][33] pad -> (tid+kk)%32 banks, 2-way
    int tid = threadIdx.x;
    // de-swizzle: B = r8 + 8*(nc + 16*a); mb = 8a + r8 -> B%8 == mb%8
    int B  = blockIdx.x;
    int r8 = B & 7;
    int tt = B >> 3;
    int nc = tt & 15;
    int aa = tt >> 4;
    int mb = 8 * aa + r8;            // 0..999
    long m0 = (long)mb * 256;
    int n0 = nc * 32;

    float acc[32];
#pragma unroll
    for (int j = 0; j < 32; j++) acc[j] = b_in[n0 + j] + b_h[n0 + j];

    for (int k0 = 0; k0 < IN_DIM; k0 += 32) {
        __syncthreads();
#pragma unroll
        for (int i = 0; i < 8; i++) {
            int f  = tid + i * 256;      // 0..2047 float4s
            int rr = f >> 3, cc = f & 7;
            float4 v = *(const float4*)(x + (m0 + rr) * IN_DIM + k0 + cc * 4);
            float* d = &xl[rr * 33 + cc * 4];   // 132B rows: scalar writes (align)
            d[0] = v.x; d[1] = v.y; d[2] = v.z; d[3] = v.w;
        }
        __syncthreads();
        const float* xrow = &xl[tid * 33];
#pragma unroll
        for (int kk = 0; kk < 32; kk++) {
            float a = xrow[kk];
            const float* wrow = w_inT + (k0 + kk) * HID + n0;  // uniform -> s_load
#pragma unroll
            for (int j = 0; j < 32; j++) acc[j] = fmaf(a, wrow[j], acc[j]);
        }
    }
    float* orow = xd + (m0 + tid) * HID + n0;
#pragma unroll
    for (int j = 0; j < 8; j++)
        *(float4*)(orow + j * 4) =
            make_float4(acc[4*j], acc[4*j+1], acc[4*j+2], acc[4*j+3]);
}

// ============================================================
// K3: the scan (R8 structure — fastest measured). 256 blocks x
//     512 threads; w_eff row in registers (fallthrough switch on
//     wave-uniform sched length; chunks of 4); act double-buffered
//     in LDS; store after barrier. Tables are bank-matched.
// ============================================================

#define PAIR2(base, ii)                                              \
    {                                                                \
        unsigned int pk = idp[ii];                                   \
        float g0 = *(const float*)((base) + (pk & 0xffffu));         \
        float g1 = *(const float*)((base) + (pk >> 16));             \
        a0 = fmaf(val[2*(ii)],     g0, a0);                          \
        a1 = fmaf(val[2*(ii) + 1], g1, a1);                          \
    }

#define CHUNK2(base, c)                                              \
    PAIR2(base, 2*(c)+0) PAIR2(base, 2*(c)+1)

__device__ __forceinline__ float sparse_accum(
    const char* base, const float (&val)[MAXNNZ],
    const unsigned int (&idp)[MAXNNZ / 2], int nch, float a_init)
{
    float a0 = a_init, a1 = 0.f;
    switch (nch) {
        case 24: CHUNK2(base, 23) [[fallthrough]];
        case 23: CHUNK2(base, 22) [[fallthrough]];
        case 22: CHUNK2(base, 21) [[fallthrough]];
        case 21: CHUNK2(base, 20) [[fallthrough]];
        case 20: CHUNK2(base, 19) [[fallthrough]];
        case 19: CHUNK2(base, 18) [[fallthrough]];
        case 18: CHUNK2(base, 17) [[fallthrough]];
        case 17: CHUNK2(base, 16) [[fallthrough]];
        case 16: CHUNK2(base, 15) [[fallthrough]];
        case 15: CHUNK2(base, 14) [[fallthrough]];
        case 14: CHUNK2(base, 13) [[fallthrough]];
        case 13: CHUNK2(base, 12) [[fallthrough]];
        case 12: CHUNK2(base, 11) [[fallthrough]];
        case 11: CHUNK2(base, 10) [[fallthrough]];
        case 10: CHUNK2(base,  9) [[fallthrough]];
        case  9: CHUNK2(base,  8) [[fallthrough]];
        case  8: CHUNK2(base,  7) [[fallthrough]];
        case  7: CHUNK2(base,  6) [[fallthrough]];
        case  6: CHUNK2(base,  5) [[fallthrough]];
        case  5: CHUNK2(base,  4) [[fallthrough]];
        case  4: CHUNK2(base,  3) [[fallthrough]];
        case  3: CHUNK2(base,  2) [[fallthrough]];
        case  2: CHUNK2(base,  1) [[fallthrough]];
        case  1: CHUNK2(base,  0) break;
        default: break;
    }
    return a0 + a1;
}

__global__ __launch_bounds__(512, 2) void scan_kernel(
    float* __restrict__ act_g,
    const float* __restrict__ val_t, const unsigned short* __restrict__ idx_t,
    const unsigned int* __restrict__ perm, const unsigned int* __restrict__ nnzR)
{
    int tid = threadIdx.x;       // rank r
    int b   = blockIdx.x;
    __shared__ float sbuf[1024];  // [0..511] region0, [512..1023] region1
    sbuf[tid] = 0.f;

    float        val[MAXNNZ];
    unsigned int idp[MAXNNZ / 2];
    {
        const float4* vp = (const float4*)(val_t + tid * MAXNNZ);
#pragma unroll
        for (int i = 0; i < MAXNNZ / 4; i++) {
            float4 v = vp[i];
            val[4*i] = v.x; val[4*i+1] = v.y; val[4*i+2] = v.z; val[4*i+3] = v.w;
        }
        const uint4* ip = (const uint4*)(idx_t + tid * MAXNNZ); // 96 u16 = 12 uint4
#pragma unroll
        for (int i = 0; i < MAXNNZ / 8; i++) {
            uint4 u = ip[i];
            idp[4*i] = u.x; idp[4*i+1] = u.y; idp[4*i+2] = u.z; idp[4*i+3] = u.w;
        }
    }
    int h = (int)perm[tid];
    int wmax = (int)nnzR[tid | 63];                 // sched S, wave-uniform
    wmax = __builtin_amdgcn_readfirstlane(wmax);
    int nch = (wmax + 3) >> 2;                      // chunks of 4 slots (2 pairs)

    float state = 0.f;
    int gi = b * HID + h;                           // index of (t=0, b, h)
    float xdv = act_g[gi];                          // prefetch t=0
    const char* sb = (const char*)sbuf;
    __syncthreads();

    for (int t = 0; t < T_STEPS; t += 2) {
        { // even step: read region0, write region1
            float xn = act_g[gi + BATCH * HID];     // t+1 <= 999 always here
            float a = sparse_accum(sb, val, idp, nch, xdv);
            state = state * OMA_F + a * ALPHA_F;
            float act = fmaxf(state, 0.f);
            sbuf[512 + h] = act;
            __syncthreads();
            act_g[gi] = act;                        // store after barrier
            gi += BATCH * HID;
            xdv = xn;
        }
        { // odd step: read region1 (+2048B), write region0
            int gn = (t < T_STEPS - 2) ? gi + BATCH * HID : gi;
            float xn = act_g[gn];
            float a = sparse_accum(sb + 2048, val, idp, nch, xdv);
            state = state * OMA_F + a * ALPHA_F;
            float act = fmaxf(state, 0.f);
            sbuf[h] = act;
            __syncthreads();
            act_g[gi] = act;                        // store after barrier
            gi += BATCH * HID;
            xdv = xn;
        }
    }
}

// ============================================================
// K4: out[m][o] = act[m]@fc_w^T + fc_b. k-tile 32 in LDS
//     (33 KB -> 4 blocks/CU), uniform s_load weights.
// ============================================================
__global__ __launch_bounds__(256, 4) void outgemm_kernel(
    const float* __restrict__ act_g, const float* __restrict__ fcT,
    const float* __restrict__ fc_b, float* __restrict__ out_g)
{
    __shared__ float al[256 * 33];
    int tid = threadIdx.x;
    long m0 = (long)blockIdx.x * 256;

    float acc[32];
#pragma unroll
    for (int o = 0; o < 32; o++) acc[o] = fc_b[o];

    for (int k0 = 0; k0 < HID; k0 += 32) {
        __syncthreads();
#pragma unroll
        for (int i = 0; i < 8; i++) {
            int f  = tid + i * 256;      // 0..2047 float4s
            int rr = f >> 3, cc = f & 7;
            float4 v = *(const float4*)(act_g + (m0 + rr) * HID + k0 + cc * 4);
            float* d = &al[rr * 33 + cc * 4];
            d[0] = v.x; d[1] = v.y; d[2] = v.z; d[3] = v.w;
        }
        __syncthreads();
        const float* arow = &al[tid * 33];
#pragma unroll
        for (int kk = 0; kk < 32; kk++) {
            float a = arow[kk];
            const float* frow = fcT + (k0 + kk) * OUT_DIM;  // uniform -> s_load
#pragma unroll
            for (int o = 0; o < 32; o++) acc[o] = fmaf(a, frow[o], acc[o]);
        }
    }
    float* orow = out_g + (m0 + tid) * OUT_DIM;
#pragma unroll
    for (int j = 0; j < 8; j++)
        *(float4*)(orow + j * 4) =
            make_float4(acc[4*j], acc[4*j+1], acc[4*j+2], acc[4*j+3]);
}

// ============================================================
extern "C" void kernel_launch(void* const* d_in, const int* in_sizes, int n_in,
                              void* d_out, int out_size, void* d_ws, size_t ws_size,
                              hipStream_t stream)
{
    const float* x      = (const float*)d_in[0];
    const float* w_in   = (const float*)d_in[1];
    const float* b_in   = (const float*)d_in[2];
    const float* w_h    = (const float*)d_in[3];
    const float* b_h    = (const float*)d_in[4];
    const float* dale   = (const float*)d_in[5];
    const float* sparse = (const float*)d_in[6];
    const float* fc_w   = (const float*)d_in[7];
    const float* fc_b   = (const float*)d_in[8];

    float* out_g = (float*)d_out;
    float* act_g = out_g + (long)T_STEPS * BATCH * OUT_DIM;  // rnn_activity slab

    char* ws = (char*)d_ws;
    float*          val_t = (float*)(ws + 0);
    unsigned short* idx_t = (unsigned short*)(ws + 196608);
    unsigned int*   perm  = (unsigned int*)(ws + 294912);
    unsigned int*   nnzR  = (unsigned int*)(ws + 296960);
    float*          w_inT = (float*)(ws + 299008);
    float*          fcT   = (float*)(ws + 561152);

    build_rank_kernel<<<1, 512, 0, stream>>>(w_h, sparse, perm, nnzR);
    fill_kernel<<<HID, 64, 0, stream>>>(w_h, dale, sparse, perm, nnzR, val_t, idx_t);
    sched_kernel<<<8, 64, 0, stream>>>(val_t, idx_t, nnzR);
    trans_kernel<<<320, 256, 0, stream>>>(w_in, fc_w, w_inT, fcT);
    ingemm_kernel<<<16000, 256, 0, stream>>>(x, w_inT, b_in, b_h, act_g);
    scan_kernel<<<256, 512, 0, stream>>>(act_g, val_t, idx_t, perm, nnzR);
    outgemm_kernel<<<1000, 256, 0, stream>>>(act_g, fcT, fc_b, out_g);
}

// Round 11
// 2003.815 us; speedup vs baseline: 1.1695x; 1.1695x over previous
//
#include <hip/hip_runtime.h>

#define T_STEPS 1000
#define BATCH   256
#define IN_DIM  128
#define HID     512
#define OUT_DIM 32
#define ALPHA_F 0.2f
#define OMA_F   0.8f
#define MAXNNZ  96   // Binomial(511,0.1) max over 512 rows ~ 75; 96 is 6.5 sigma
#define BDEPTH  20   // per-(lane,bank) bucket depth; P(overflow) ~ 0

// ---- workspace layout (byte offsets, all 16B aligned) ----
// val_t : float  [HID][MAXNNZ]   rank-ordered rows      @ 0        (196608 B)
// idx_t : ushort [HID][MAXNNZ]   byte offsets (j*4)     @ 196608   (98304 B)
// perm  : uint   [HID]           rank -> row            @ 294912   (2048 B)
// nnzR  : uint   [HID]           nnz (later: sched S)   @ 296960   (2048 B)
// w_inT : float  [IN_DIM][HID]                          @ 299008   (262144 B)
// fcT   : float  [HID][OUT_DIM]                         @ 561152   (65536 B)

// ============================================================
// K2a: counts + deterministic rank (stable sort by (c, h)).
// ============================================================
__global__ __launch_bounds__(512) void build_rank_kernel(
    const float* __restrict__ w_h, const float* __restrict__ sparse,
    unsigned int* __restrict__ perm, unsigned int* __restrict__ nnzR)
{
    int tid = threadIdx.x;           // row h
    __shared__ int cnt_sh[HID];

    const float4* wr4 = (const float4*)(w_h    + tid * HID);
    const float4* sr4 = (const float4*)(sparse + tid * HID);
    int cnt = 0;
    for (int j4 = 0; j4 < HID / 4; j4++) {
        float4 w = wr4[j4];
        float4 s = sr4[j4];
        if (w.x > 0.f && s.x > 0.5f) cnt++;
        if (w.y > 0.f && s.y > 0.5f) cnt++;
        if (w.z > 0.f && s.z > 0.5f) cnt++;
        if (w.w > 0.f && s.w > 0.5f) cnt++;
    }
    int c = min(cnt, MAXNNZ);

    cnt_sh[tid] = c;
    __syncthreads();
    int rank = 0;
    for (int j = 0; j < HID; j++) {
        int cj = cnt_sh[j];                     // broadcast read
        rank += (cj < c) || (cj == c && j < tid);
    }
    perm[rank] = (unsigned int)tid;
    nnzR[rank] = (unsigned int)c;
}

// ============================================================
// K2b: wave-parallel fill, one rank per block (1 wave).
//      Ascending-j compaction via ballot prefix (deterministic).
// ============================================================
__global__ __launch_bounds__(64) void fill_kernel(
    const float* __restrict__ w_h, const float* __restrict__ dale,
    const float* __restrict__ sparse,
    const unsigned int* __restrict__ perm, const unsigned int* __restrict__ nnzR,
    float* __restrict__ val_t, unsigned short* __restrict__ idx_t)
{
    int r    = blockIdx.x;           // rank
    int lane = threadIdx.x;          // 0..63
    int h = (int)perm[r];
    int c = (int)nnzR[r];

    float*          vout = val_t + r * MAXNNZ;
    unsigned short* iout = idx_t + r * MAXNNZ;

    for (int k = lane; k < MAXNNZ; k += 64)
        if (k >= c) { vout[k] = 0.f; iout[k] = 0; }

    unsigned long long lt = (1ull << lane) - 1ull;
    int pos_base = 0;
#pragma unroll
    for (int ch = 0; ch < 8; ch++) {
        int j = ch * 64 + lane;
        float w = w_h[h * HID + j];
        float s = sparse[h * HID + j];
        bool pred = (w > 0.f) && (s > 0.5f);
        unsigned long long m = __ballot(pred);
        if (pred) {
            int pos = pos_base + (int)__popcll(m & lt);
            if (pos < MAXNNZ) {
                vout[pos] = w * dale[j];
                iout[pos] = (unsigned short)(j * 4);   // LDS byte offset
            }
        }
        pos_base += (int)__popcll(m);
    }
}

// ============================================================
// K2d: capped gather scheduler (R8 schedule quality, ~20x cheaper).
//  1 wave per scan wave. S = wave-max nnz (keeps nnz-sort gradient,
//  444 total slots). Per slot, 2 propose/resolve rounds:
//    - propose: rotated-ffs over (bm & ~claimed)
//    - resolve: LDS multi-write of lane-id to wbuf[g][bank] (HW
//      lane-priority pick is fixed -> deterministic), read back;
//    - claim mask: 5-step shfl_xor OR-reduce within 32-lane group.
//  Forced fallback when rem == S-s guarantees zero drops (invariant
//  rem <= S-s, proven in R8). Pad lanes share one free bank
//  (same addr -> broadcast). Permutation of a commutative sum.
// ============================================================
__global__ __launch_bounds__(64) void sched_kernel(
    float* __restrict__ val_t, unsigned short* __restrict__ idx_t,
    unsigned int* __restrict__ nnzR)
{
    int w    = blockIdx.x;           // scan-wave id 0..7
    int lane = threadIdx.x;          // 0..63
    int rank = w * 64 + lane;
    int g    = lane >> 5;            // phase-group 0/1
    int l32  = lane & 31;

    __shared__ unsigned short entb[64][32][BDEPTH]; // (src<<9)|word
    __shared__ unsigned char  cntb[64][32];
    __shared__ unsigned char  outsrc[64][MAXNNZ];
    __shared__ float          vll[64][MAXNNZ];
    __shared__ volatile int   wbuf[2][32];

    int c = (int)nnzR[rank];
    int S = c;
#pragma unroll
    for (int off = 32; off; off >>= 1) S = max(S, __shfl_xor(S, off));
    // S = wave-max nnz (<= MAXNNZ by construction)

    for (int b = 0; b < 32; b++) cntb[lane][b] = 0;
    for (int e = 0; e < MAXNNZ; e++) {
        vll[lane][e]    = val_t[rank * MAXNNZ + e];
        outsrc[lane][e] = 255;
    }
    unsigned int bm = 0;
    int rem = 0;
    for (int e = 0; e < c; e++) {
        int word = ((int)idx_t[rank * MAXNNZ + e]) >> 2;  // 0..511
        int b = word & 31;
        int k = (int)cntb[lane][b];
        if (k < BDEPTH) {
            entb[lane][b][k] = (unsigned short)((e << 9) | word);
            cntb[lane][b] = (unsigned char)(k + 1);
            bm |= 1u << b;
            rem++;
        }
    }

    for (int s = 0; s < MAXNNZ; s++) {
        if (s < S) {
            unsigned int claimed = 0;            // my group's claimed banks
            int myb = -1;
#pragma unroll
            for (int round = 0; round < 2; round++) {
                int prop = -1;
                if (myb < 0 && rem > 0) {
                    unsigned int avail = bm & ~claimed;
                    if (avail) {
                        int rot = (l32 * 7 + s * 3 + round * 11) & 31;
                        unsigned int av2 = (avail >> rot) | (avail << ((32 - rot) & 31));
                        prop = (__ffs(av2) - 1 + rot) & 31;
                    }
                }
                if (prop >= 0) wbuf[g][prop] = lane;        // race: HW lane priority
                int won = 0;
                if (prop >= 0 && wbuf[g][prop] == lane) { myb = prop; won = 1; }
                unsigned int cm = won ? (1u << myb) : 0u;
#pragma unroll
                for (int off = 16; off; off >>= 1)
                    cm |= (unsigned int)__shfl_xor((int)cm, off, 32);
                claimed |= cm;
            }
            if (myb < 0 && rem > 0 && rem >= S - s) {       // forced (rare)
                unsigned int a = bm & ~claimed;
                myb = a ? (__ffs(a) - 1) : (__ffs(bm) - 1);
            }
            if (myb >= 0) {
                int k = (int)cntb[lane][myb] - 1;
                unsigned short pk = entb[lane][myb][k];
                cntb[lane][myb] = (unsigned char)k;
                if (k == 0) bm &= ~(1u << myb);
                outsrc[lane][s] = (unsigned char)(pk >> 9);
                idx_t[rank * MAXNNZ + s] = (unsigned short)((pk & 511) * 4);
                rem--;
            } else {
                unsigned int freeb = ~claimed;              // pad: shared free bank
                int pb = freeb ? (__ffs(freeb) - 1) : 0;
                idx_t[rank * MAXNNZ + s] = (unsigned short)(pb * 4);
            }
        } else {
            idx_t[rank * MAXNNZ + s] = 0;        // tail pad (chunk rounding)
        }
    }
    nnzR[rank] = (unsigned int)S;

    for (int s = 0; s < MAXNNZ; s++) {
        int src = outsrc[lane][s];
        val_t[rank * MAXNNZ + s] = (src == 255) ? 0.f : vll[lane][src];
    }
}

// ============================================================
// K2c: weight transposes, grid-parallel.
// ============================================================
__global__ __launch_bounds__(256) void trans_kernel(
    const float* __restrict__ w_in, const float* __restrict__ fc_w,
    float* __restrict__ w_inT, float* __restrict__ fcT)
{
    int o = blockIdx.x * 256 + threadIdx.x;
    if (o < IN_DIM * HID) {
        int k = o / HID, n = o % HID;          // w_inT[k][n] = w_in[n][k]
        w_inT[o] = w_in[n * IN_DIM + k];
    } else {
        int o2 = o - IN_DIM * HID;
        if (o2 < HID * OUT_DIM) {
            int k = o2 / OUT_DIM, oo = o2 % OUT_DIM;   // fcT[k][o] = fc_w[o][k]
            fcT[o2] = fc_w[oo * HID + k];
        }
    }
}

// ============================================================
// K1: xd[m][h] = x[m]@w_in^T + b_in + b_h  into activity slab.
//     Grid 16000 = 1000 m-tiles x 16 n-chunks (XCD-swizzled).
//     k-tile 32 in LDS (33 KB -> 4 blocks/CU, 16 waves/CU).
// ============================================================
__global__ __launch_bounds__(256, 4) void ingemm_kernel(
    const float* __restrict__ x, const float* __restrict__ w_inT,
    const float* __restrict__ b_in, const float* __restrict__ b_h,
    float* __restrict__ xd)
{
    __shared__ float xl[256 * 33];   // [row][33] pad -> (tid+kk)%32 banks, 2-way
    int tid = threadIdx.x;
    // de-swizzle: B = r8 + 8*(nc + 16*a); mb = 8a + r8 -> B%8 == mb%8
    int B  = blockIdx.x;
    int r8 = B & 7;
    int tt = B >> 3;
    int nc = tt & 15;
    int aa = tt >> 4;
    int mb = 8 * aa + r8;            // 0..999
    long m0 = (long)mb * 256;
    int n0 = nc * 32;

    float acc[32];
#pragma unroll
    for (int j = 0; j < 32; j++) acc[j] = b_in[n0 + j] + b_h[n0 + j];

    for (int k0 = 0; k0 < IN_DIM; k0 += 32) {
        __syncthreads();
#pragma unroll
        for (int i = 0; i < 8; i++) {
            int f  = tid + i * 256;      // 0..2047 float4s
            int rr = f >> 3, cc = f & 7;
            float4 v = *(const float4*)(x + (m0 + rr) * IN_DIM + k0 + cc * 4);
            float* d = &xl[rr * 33 + cc * 4];   // 132B rows: scalar writes (align)
            d[0] = v.x; d[1] = v.y; d[2] = v.z; d[3] = v.w;
        }
        __syncthreads();
        const float* xrow = &xl[tid * 33];
#pragma unroll
        for (int kk = 0; kk < 32; kk++) {
            float a = xrow[kk];
            const float* wrow = w_inT + (k0 + kk) * HID + n0;  // uniform -> s_load
#pragma unroll
            for (int j = 0; j < 32; j++) acc[j] = fmaf(a, wrow[j], acc[j]);
        }
    }
    float* orow = xd + (m0 + tid) * HID + n0;
#pragma unroll
    for (int j = 0; j < 8; j++)
        *(float4*)(orow + j * 4) =
            make_float4(acc[4*j], acc[4*j+1], acc[4*j+2], acc[4*j+3]);
}

// ============================================================
// K3: the scan (R8 structure — fastest measured). 256 blocks x
//     512 threads; w_eff row in registers (fallthrough switch on
//     wave-uniform sched length; chunks of 4); act double-buffered
//     in LDS; store after barrier. Tables are bank-matched.
// ============================================================

#define PAIR2(base, ii)                                              \
    {                                                                \
        unsigned int pk = idp[ii];                                   \
        float g0 = *(const float*)((base) + (pk & 0xffffu));         \
        float g1 = *(const float*)((base) + (pk >> 16));             \
        a0 = fmaf(val[2*(ii)],     g0, a0);                          \
        a1 = fmaf(val[2*(ii) + 1], g1, a1);                          \
    }

#define CHUNK2(base, c)                                              \
    PAIR2(base, 2*(c)+0) PAIR2(base, 2*(c)+1)

__device__ __forceinline__ float sparse_accum(
    const char* base, const float (&val)[MAXNNZ],
    const unsigned int (&idp)[MAXNNZ / 2], int nch, float a_init)
{
    float a0 = a_init, a1 = 0.f;
    switch (nch) {
        case 24: CHUNK2(base, 23) [[fallthrough]];
        case 23: CHUNK2(base, 22) [[fallthrough]];
        case 22: CHUNK2(base, 21) [[fallthrough]];
        case 21: CHUNK2(base, 20) [[fallthrough]];
        case 20: CHUNK2(base, 19) [[fallthrough]];
        case 19: CHUNK2(base, 18) [[fallthrough]];
        case 18: CHUNK2(base, 17) [[fallthrough]];
        case 17: CHUNK2(base, 16) [[fallthrough]];
        case 16: CHUNK2(base, 15) [[fallthrough]];
        case 15: CHUNK2(base, 14) [[fallthrough]];
        case 14: CHUNK2(base, 13) [[fallthrough]];
        case 13: CHUNK2(base, 12) [[fallthrough]];
        case 12: CHUNK2(base, 11) [[fallthrough]];
        case 11: CHUNK2(base, 10) [[fallthrough]];
        case 10: CHUNK2(base,  9) [[fallthrough]];
        case  9: CHUNK2(base,  8) [[fallthrough]];
        case  8: CHUNK2(base,  7) [[fallthrough]];
        case  7: CHUNK2(base,  6) [[fallthrough]];
        case  6: CHUNK2(base,  5) [[fallthrough]];
        case  5: CHUNK2(base,  4) [[fallthrough]];
        case  4: CHUNK2(base,  3) [[fallthrough]];
        case  3: CHUNK2(base,  2) [[fallthrough]];
        case  2: CHUNK2(base,  1) [[fallthrough]];
        case  1: CHUNK2(base,  0) break;
        default: break;
    }
    return a0 + a1;
}

__global__ __launch_bounds__(512, 2) void scan_kernel(
    float* __restrict__ act_g,
    const float* __restrict__ val_t, const unsigned short* __restrict__ idx_t,
    const unsigned int* __restrict__ perm, const unsigned int* __restrict__ nnzR)
{
    int tid = threadIdx.x;       // rank r
    int b   = blockIdx.x;
    __shared__ float sbuf[1024];  // [0..511] region0, [512..1023] region1
    sbuf[tid] = 0.f;

    float        val[MAXNNZ];
    unsigned int idp[MAXNNZ / 2];
    {
        const float4* vp = (const float4*)(val_t + tid * MAXNNZ);
#pragma unroll
        for (int i = 0; i < MAXNNZ / 4; i++) {
            float4 v = vp[i];
            val[4*i] = v.x; val[4*i+1] = v.y; val[4*i+2] = v.z; val[4*i+3] = v.w;
        }
        const uint4* ip = (const uint4*)(idx_t + tid * MAXNNZ); // 96 u16 = 12 uint4
#pragma unroll
        for (int i = 0; i < MAXNNZ / 8; i++) {
            uint4 u = ip[i];
            idp[4*i] = u.x; idp[4*i+1] = u.y; idp[4*i+2] = u.z; idp[4*i+3] = u.w;
        }
    }
    int h = (int)perm[tid];
    int wmax = (int)nnzR[tid | 63];                 // sched S, wave-uniform
    wmax = __builtin_amdgcn_readfirstlane(wmax);
    int nch = (wmax + 3) >> 2;                      // chunks of 4 slots (2 pairs)

    float state = 0.f;
    int gi = b * HID + h;                           // index of (t=0, b, h)
    float xdv = act_g[gi];                          // prefetch t=0
    const char* sb = (const char*)sbuf;
    __syncthreads();

    for (int t = 0; t < T_STEPS; t += 2) {
        { // even step: read region0, write region1
            float xn = act_g[gi + BATCH * HID];     // t+1 <= 999 always here
            float a = sparse_accum(sb, val, idp, nch, xdv);
            state = state * OMA_F + a * ALPHA_F;
            float act = fmaxf(state, 0.f);
            sbuf[512 + h] = act;
            __syncthreads();
            act_g[gi] = act;                        // store after barrier
            gi += BATCH * HID;
            xdv = xn;
        }
        { // odd step: read region1 (+2048B), write region0
            int gn = (t < T_STEPS - 2) ? gi + BATCH * HID : gi;
            float xn = act_g[gn];
            float a = sparse_accum(sb + 2048, val, idp, nch, xdv);
            state = state * OMA_F + a * ALPHA_F;
            float act = fmaxf(state, 0.f);
            sbuf[h] = act;
            __syncthreads();
            act_g[gi] = act;                        // store after barrier
            gi += BATCH * HID;
            xdv = xn;
        }
    }
}

// ============================================================
// K4: out[m][o] = act[m]@fc_w^T + fc_b. k-tile 32 in LDS
//     (33 KB -> 4 blocks/CU), uniform s_load weights.
// ============================================================
__global__ __launch_bounds__(256, 4) void outgemm_kernel(
    const float* __restrict__ act_g, const float* __restrict__ fcT,
    const float* __restrict__ fc_b, float* __restrict__ out_g)
{
    __shared__ float al[256 * 33];
    int tid = threadIdx.x;
    long m0 = (long)blockIdx.x * 256;

    float acc[32];
#pragma unroll
    for (int o = 0; o < 32; o++) acc[o] = fc_b[o];

    for (int k0 = 0; k0 < HID; k0 += 32) {
        __syncthreads();
#pragma unroll
        for (int i = 0; i < 8; i++) {
            int f  = tid + i * 256;      // 0..2047 float4s
            int rr = f >> 3, cc = f & 7;
            float4 v = *(const float4*)(act_g + (m0 + rr) * HID + k0 + cc * 4);
            float* d = &al[rr * 33 + cc * 4];
            d[0] = v.x; d[1] = v.y; d[2] = v.z; d[3] = v.w;
        }
        __syncthreads();
        const float* arow = &al[tid * 33];
#pragma unroll
        for (int kk = 0; kk < 32; kk++) {
            float a = arow[kk];
            const float* frow = fcT + (k0 + kk) * OUT_DIM;  // uniform -> s_load
#pragma unroll
            for (int o = 0; o < 32; o++) acc[o] = fmaf(a, frow[o], acc[o]);
        }
    }
    float* orow = out_g + (m0 + tid) * OUT_DIM;
#pragma unroll
    for (int j = 0; j < 8; j++)
        *(float4*)(orow + j * 4) =
            make_float4(acc[4*j], acc[4*j+1], acc[4*j+2], acc[4*j+3]);
}

// ============================================================
extern "C" void kernel_launch(void* const* d_in, const int* in_sizes, int n_in,
                              void* d_out, int out_size, void* d_ws, size_t ws_size,
                              hipStream_t stream)
{
    const float* x      = (const float*)d_in[0];
    const float* w_in   = (const float*)d_in[1];
    const float* b_in   = (const float*)d_in[2];
    const float* w_h    = (const float*)d_in[3];
    const float* b_h    = (const float*)d_in[4];
    const float* dale   = (const float*)d_in[5];
    const float* sparse = (const float*)d_in[6];
    const float* fc_w   = (const float*)d_in[7];
    const float* fc_b   = (const float*)d_in[8];

    float* out_g = (float*)d_out;
    float* act_g = out_g + (long)T_STEPS * BATCH * OUT_DIM;  // rnn_activity slab

    char* ws = (char*)d_ws;
    float*          val_t = (float*)(ws + 0);
    unsigned short* idx_t = (unsigned short*)(ws + 196608);
    unsigned int*   perm  = (unsigned int*)(ws + 294912);
    unsigned int*   nnzR  = (unsigned int*)(ws + 296960);
    float*          w_inT = (float*)(ws + 299008);
    float*          fcT   = (float*)(ws + 561152);

    build_rank_kernel<<<1, 512, 0, stream>>>(w_h, sparse, perm, nnzR);
    fill_kernel<<<HID, 64, 0, stream>>>(w_h, dale, sparse, perm, nnzR, val_t, idx_t);
    sched_kernel<<<8, 64, 0, stream>>>(val_t, idx_t, nnzR);
    trans_kernel<<<320, 256, 0, stream>>>(w_in, fc_w, w_inT, fcT);
    ingemm_kernel<<<16000, 256, 0, stream>>>(x, w_inT, b_in, b_h, act_g);
    scan_kernel<<<256, 512, 0, stream>>>(act_g, val_t, idx_t, perm, nnzR);
    outgemm_kernel<<<1000, 256, 0, stream>>>(act_g, fcT, fc_b, out_g);
}